// Round 13
// baseline (331.329 us; speedup 1.0000x reference)
//
#include <hip/hip_runtime.h>
#include <hip/hip_bf16.h>
#include <math.h>

typedef unsigned short bhalf;
typedef unsigned int u32;
typedef unsigned long long u64;
typedef __attribute__((ext_vector_type(8))) short s16x8;
typedef __attribute__((ext_vector_type(4))) float f32x4;

#define SCALE_QK 0.15811388300841898f
#define K2E (SCALE_QK * 1.4426950408889634f)
#define NEG_INF (-3.402823466e38f)

__device__ __forceinline__ float bf2f(bhalf u){
    union { unsigned int i; float f; } v; v.i = ((unsigned int)u) << 16; return v.f;
}
__device__ __forceinline__ bhalf f2bf(float f){
    unsigned int x = __float_as_uint(f);
    unsigned int r = (x + 0x7fffu + ((x >> 16) & 1u)) >> 16;
    return (bhalf)r;
}
__device__ __forceinline__ float fexp2(float x){
    float r; asm("v_exp_f32 %0, %1" : "=v"(r) : "v"(x)); return r;
}
__device__ __forceinline__ u32 cvtpk(float lo, float hi){
    u32 r; asm("v_cvt_pk_bf16_f32 %0, %1, %2" : "=v"(r) : "v"(lo), "v"(hi)); return r;
}

struct WT12 { const float* in[12]; bhalf* out[12]; };

// ================================================================ mega_prep: posnet | transpose | resize | LN+copy
// blocks: [0,16) posnet (4 blocks/box, layer-3 sliced), [16,456) transpose, [456,600) resize,
//         [600,21080) ln_fused. 320 threads.
struct PrepArgs {
    const float *itok, *g_obj, *b_obj; bhalf *q_in, *x_la;
    WT12 wt;
    const float *gmask, *smask, *sgv; float *gm_all, *sig;
    const float *box, *W1, *b1, *W2, *b2, *W3, *b3; float* tok;
};

__global__ __launch_bounds__(320) void mega_prep(PrepArgs a){
    __shared__ float smem[64 * 65];
    const int bid = blockIdx.x, tid = threadIdx.x;
    if (bid < 16){
        // ---- PositionNet: 4 blocks per box, layer-3 sliced 4 ways.
        float* emb = smem; float* h1 = smem + 128; float* h2 = smem + 640;
        const int bb = bid >> 2, sl = bid & 3;
        for (int t = tid; t < 128; t += 320){
            const int i = t >> 4, jj = t & 15, j = jj & 7;
            const float f = powf(100.f, (float)i * 0.125f);
            const float v = f * a.box[bb * 8 + j];
            emb[t] = (jj < 8) ? sinf(v) : cosf(v);
        }
        __syncthreads();
        for (int t = tid; t < 512; t += 320){
            float a0 = a.b1[t], a1 = 0.f, a2 = 0.f, a3 = 0.f;
#pragma unroll 8
            for (int k = 0; k < 32; ++k){
                a0 += emb[k]      * a.W1[k * 512 + t];
                a1 += emb[k + 32] * a.W1[(k + 32) * 512 + t];
                a2 += emb[k + 64] * a.W1[(k + 64) * 512 + t];
                a3 += emb[k + 96] * a.W1[(k + 96) * 512 + t];
            }
            const float x = (a0 + a1) + (a2 + a3);
            h1[t] = x / (1.f + __expf(-x));
        }
        __syncthreads();
        for (int t = tid; t < 512; t += 320){
            float a0 = a.b2[t], a1 = 0.f, a2 = 0.f, a3 = 0.f;
#pragma unroll 8
            for (int k = 0; k < 128; ++k){
                a0 += h1[k]       * a.W2[k * 512 + t];
                a1 += h1[k + 128] * a.W2[(k + 128) * 512 + t];
                a2 += h1[k + 256] * a.W2[(k + 256) * 512 + t];
                a3 += h1[k + 384] * a.W2[(k + 384) * 512 + t];
            }
            const float x = (a0 + a1) + (a2 + a3);
            h2[t] = x / (1.f + __expf(-x));
        }
        __syncthreads();
        if (tid < 192){
            const int t = sl * 192 + tid;
            float a0 = a.b3[t], a1 = 0.f, a2 = 0.f, a3 = 0.f;
#pragma unroll 8
            for (int k = 0; k < 128; ++k){
                a0 += h2[k]       * a.W3[k * 768 + t];
                a1 += h2[k + 128] * a.W3[(k + 128) * 768 + t];
                a2 += h2[k + 256] * a.W3[(k + 256) * 768 + t];
                a3 += h2[k + 384] * a.W3[(k + 384) * 768 + t];
            }
            a.tok[bb * 768 + t] = (a0 + a1) + (a2 + a3);
        }
    } else if (bid < 456){
        // ---- weight transpose (LDS-tiled), b = bid-16
        float (*T)[65] = (float(*)[65])smem;
        const int b = bid - 16;
        int w, t, K;
        if (b < 200){ w = b / 25; t = b % 25; K = 320; }
        else        { w = 8 + (b - 200) / 60; t = (b - 200) % 60; K = 768; }
        const int k0 = (t / 5) * 64, n0 = (t % 5) * 64;
        const float* in = a.wt.in[w];
        bhalf* out = a.wt.out[w];
        const int c = tid & 63, wv = tid >> 6;
        if (tid < 256){
#pragma unroll
            for (int r = 0; r < 16; ++r)
                T[wv + r * 4][c] = in[(long)(k0 + wv + r * 4) * 320 + n0 + c];
        }
        __syncthreads();
        if (tid < 256){
#pragma unroll
            for (int r = 0; r < 16; ++r)
                out[(long)(n0 + wv + r * 4) * K + k0 + c] = f2bf(T[c][wv + r * 4]);
        }
    } else if (bid < 600){
        // ---- resize (8x down, 4-tap avg), b = bid-456
        if (tid < 256){
            const int b = bid - 456;
            const int p = b >> 4;
            const int i = (b & 15) * 256 + tid;
            const int y = i >> 6, x = i & 63;
            const int o = (8 * y + 3) * 512 + 8 * x + 3;
            const float* s; float* dst;
            if (p < 4){ s = a.gmask + (long)p * 262144; dst = a.gm_all + p * 4096; }
            else if (p == 4){ s = a.smask; dst = a.gm_all + 4 * 4096; }
            else { s = a.sgv + (long)(p - 5) * 262144; dst = a.sig + (p - 5) * 4096; }
            dst[i] = 0.25f * (s[o] + s[o + 1] + s[o + 512] + s[o + 513]);
        }
    } else {
        // ---- LN (rows 0..16383 of itok[4096..]) + bf16 copy (rows 16384..20479 -> x_la)
        const int row = bid - 600, c = tid;
        if (row >= 16384){
            const int rr = row - 16384;
            a.x_la[(long)rr * 320 + c] = f2bf(a.itok[(long)rr * 320 + c]);
            return;
        }
        float* rs = smem; float* rq = smem + 8;
        const float v = a.itok[(long)(4096 + row) * 320 + c];
        float s = v, sq = v * v;
#pragma unroll
        for (int o = 1; o < 64; o <<= 1){ s += __shfl_xor(s, o); sq += __shfl_xor(sq, o); }
        const int wv = tid >> 6;
        if ((tid & 63) == 0){ rs[wv] = s; rq[wv] = sq; }
        __syncthreads();
        if (tid == 0){
            float ts = 0, tq = 0;
#pragma unroll
            for (int w = 0; w < 5; ++w){ ts += rs[w]; tq += rq[w]; }
            rs[0] = ts; rq[0] = tq;
        }
        __syncthreads();
        const float mean = rs[0] * (1.f / 320.f);
        const float var  = rq[0] * (1.f / 320.f) - mean * mean;
        const float inv  = rsqrtf(var + 1e-5f);
        a.q_in[(long)row * 320 + c] = f2bf((v - mean) * inv * a.g_obj[c] + a.b_obj[c]);
    }
}

// ================================================================ mega_mask: maskbits | assemble. 256 threads.
__global__ __launch_bounds__(256) void mega_mask(
    const float* __restrict__ gm_all, u64* __restrict__ mb,
    const float* __restrict__ context, const float* __restrict__ imgf,
    const float* __restrict__ bgf, const float* __restrict__ boxtok, bhalf* __restrict__ out)
{
    __shared__ float smem[5440];
    const int tid = threadIdx.x;
    if (blockIdx.x < 256){
        const int r = blockIdx.x;
        const int i0 = (r & 63) << 6, j0 = (r >> 6) << 10;
        float* gi = smem;          // [5][64]
        float* gj = smem + 320;    // [5][1024]
        for (int idx = tid; idx < 5 * 64; idx += 256)
            gi[idx] = gm_all[(idx >> 6) * 4096 + i0 + (idx & 63)];
        for (int idx = tid; idx < 5 * 1024; idx += 256)
            gj[idx] = gm_all[(idx >> 10) * 4096 + j0 + (idx & 1023)];
        __syncthreads();
        const int lane = tid & 63, wave = tid >> 6;
        const float a0 = gi[lane], a1 = gi[64 + lane], a2 = gi[128 + lane],
                    a3 = gi[192 + lane], a4 = gi[256 + lane];
        for (int ww = wave; ww < 16; ww += 4){
            u64 m = 0;
            for (int j = 0; j < 64; ++j){
                const int jj = (ww << 6) + j;
                const float dot = a0 * gj[jj] + a1 * gj[1024 + jj] + a2 * gj[2048 + jj]
                                + a3 * gj[3072 + jj] + a4 * gj[4096 + jj];
                m |= (u64)(dot != 0.f) << j;
            }
            mb[(long)((j0 >> 6) + ww) * 4096 + (i0 + lane)] = m;
        }
    } else {
        const int idx = (blockIdx.x - 256) * 256 + tid;
        const int i = idx / (336 * 768);
        const int r = (idx / 768) % 336;
        const int c = idx % 768;
        float v;
        if (i < 4){
            if (r < 77)       v = context[((long)(1 + i) * 77 + r) * 768 + c];
            else if (r < 334) v = imgf[((long)i * 257 + (r - 77)) * 768 + c];
            else if (r == 334) v = boxtok[i * 768 + c];
            else v = 0.f;
        } else {
            if (r < 77)       v = context[(long)r * 768 + c];
            else if (r < 334) v = bgf[(long)(r - 77) * 768 + c];
            else v = 0.f;
        }
        out[idx] = f2bf(v);
    }
}

// ================================================================ GEMM bodies: 1-deep software pipeline
// (loads for k+1 issued as named SSA values BEFORE k's MFMAs -> guaranteed in-flight overlap;
//  r12 showed compiler recycles load regs when left to itself: VGPR pinned at 56, no speedup)
template<int K>
__device__ __forceinline__ void gemm5_body(
    int bx, int by, const bhalf* __restrict__ A, const bhalf* __restrict__ Wt,
    bhalf* __restrict__ Cbf, int M, int kdm, float scale)
{
    const int wave = threadIdx.x >> 6, lane = threadIdx.x & 63;
    const int m0 = bx * 64 + wave * 16;
    const int n0 = by * 64;
    int mrow = m0 + (lane & 15); if (mrow > M - 1) mrow = M - 1;
    const int klo = (lane >> 4) * 8;
    const bhalf* ap = A + (long)mrow * K + klo;
    const bhalf* wp = Wt + (long)(n0 + (lane & 15)) * K + klo;
    const f32x4 fz = {0.f, 0.f, 0.f, 0.f};
    f32x4 acc[4]; acc[0] = fz; acc[1] = fz; acc[2] = fz; acc[3] = fz;
    s16x8 a_c  = *(const s16x8*)(ap);
    s16x8 b_c0 = *(const s16x8*)(wp);
    s16x8 b_c1 = *(const s16x8*)(wp + (long)16 * K);
    s16x8 b_c2 = *(const s16x8*)(wp + (long)32 * K);
    s16x8 b_c3 = *(const s16x8*)(wp + (long)48 * K);
#pragma unroll
    for (int k0 = 0; k0 < K; k0 += 32){
        const int kn = (k0 + 32 < K) ? k0 + 32 : k0;   // last iter: redundant reload (safe)
        s16x8 a_n  = *(const s16x8*)(ap + kn);
        s16x8 b_n0 = *(const s16x8*)(wp + kn);
        s16x8 b_n1 = *(const s16x8*)(wp + (long)16 * K + kn);
        s16x8 b_n2 = *(const s16x8*)(wp + (long)32 * K + kn);
        s16x8 b_n3 = *(const s16x8*)(wp + (long)48 * K + kn);
        acc[0] = __builtin_amdgcn_mfma_f32_16x16x32_bf16(a_c, b_c0, acc[0], 0, 0, 0);
        acc[1] = __builtin_amdgcn_mfma_f32_16x16x32_bf16(a_c, b_c1, acc[1], 0, 0, 0);
        acc[2] = __builtin_amdgcn_mfma_f32_16x16x32_bf16(a_c, b_c2, acc[2], 0, 0, 0);
        acc[3] = __builtin_amdgcn_mfma_f32_16x16x32_bf16(a_c, b_c3, acc[3], 0, 0, 0);
        a_c = a_n; b_c0 = b_n0; b_c1 = b_n1; b_c2 = b_n2; b_c3 = b_n3;
    }
    const int rb = m0 + (lane >> 4) * 4;
    int rin[4], rn[4];
#pragma unroll
    for (int r = 0; r < 4; ++r){ const int row = rb + r; rin[r] = row / kdm; rn[r] = row % kdm; }
#pragma unroll
    for (int t = 0; t < 4; ++t){
        const int col = n0 + t * 16 + (lane & 15);
        const int hh = col / 40, cc = col % 40;
#pragma unroll
        for (int r = 0; r < 4; ++r){
            if (rb + r >= M) continue;
            Cbf[(((long)rin[r] * 8 + hh) * kdm + rn[r]) * 40 + cc] = f2bf(acc[t][r] * scale);
        }
    }
}

template<int K>
__device__ __forceinline__ void gemm_vt_body(
    int bx, int by, const bhalf* __restrict__ A, const bhalf* __restrict__ Wt,
    bhalf* __restrict__ Vt, int M, int vt_ns, int PAD, bhalf (*Tsh)[72])
{
    const int wave = threadIdx.x >> 6, lane = threadIdx.x & 63;
    const int m0 = bx * 64 + wave * 16;
    const int n0 = by * 64;
    int mrow = m0 + (lane & 15); if (mrow > M - 1) mrow = M - 1;
    const int klo = (lane >> 4) * 8;
    const bhalf* ap = A + (long)mrow * K + klo;
    const bhalf* wp = Wt + (long)(n0 + (lane & 15)) * K + klo;
    const f32x4 fz = {0.f, 0.f, 0.f, 0.f};
    f32x4 acc[4]; acc[0] = fz; acc[1] = fz; acc[2] = fz; acc[3] = fz;
    s16x8 a_c  = *(const s16x8*)(ap);
    s16x8 b_c0 = *(const s16x8*)(wp);
    s16x8 b_c1 = *(const s16x8*)(wp + (long)16 * K);
    s16x8 b_c2 = *(const s16x8*)(wp + (long)32 * K);
    s16x8 b_c3 = *(const s16x8*)(wp + (long)48 * K);
#pragma unroll
    for (int k0 = 0; k0 < K; k0 += 32){
        const int kn = (k0 + 32 < K) ? k0 + 32 : k0;
        s16x8 a_n  = *(const s16x8*)(ap + kn);
        s16x8 b_n0 = *(const s16x8*)(wp + kn);
        s16x8 b_n1 = *(const s16x8*)(wp + (long)16 * K + kn);
        s16x8 b_n2 = *(const s16x8*)(wp + (long)32 * K + kn);
        s16x8 b_n3 = *(const s16x8*)(wp + (long)48 * K + kn);
        acc[0] = __builtin_amdgcn_mfma_f32_16x16x32_bf16(a_c, b_c0, acc[0], 0, 0, 0);
        acc[1] = __builtin_amdgcn_mfma_f32_16x16x32_bf16(a_c, b_c1, acc[1], 0, 0, 0);
        acc[2] = __builtin_amdgcn_mfma_f32_16x16x32_bf16(a_c, b_c2, acc[2], 0, 0, 0);
        acc[3] = __builtin_amdgcn_mfma_f32_16x16x32_bf16(a_c, b_c3, acc[3], 0, 0, 0);
        a_c = a_n; b_c0 = b_n0; b_c1 = b_n1; b_c2 = b_n2; b_c3 = b_n3;
    }
    const int hi = lane >> 4, l15 = lane & 15;
#pragma unroll
    for (int t = 0; t < 4; ++t)
#pragma unroll
        for (int r = 0; r < 4; ++r)
            Tsh[wave * 16 + hi * 4 + r][t * 16 + l15] = f2bf(acc[t][r]);
    __syncthreads();
    const int c = threadIdx.x & 63, jq = threadIdx.x >> 6;
    const int jbase = bx * 64 + jq * 16;
    if (jbase >= PAD) return;
    bhalf* vp = Vt + (long)(n0 + c) * vt_ns + jbase;
    if (jbase + 16 <= M){
        u32 wb[8];
#pragma unroll
        for (int p = 0; p < 8; ++p)
            wb[p] = (u32)Tsh[jq * 16 + 2 * p][c] | ((u32)Tsh[jq * 16 + 2 * p + 1][c] << 16);
        *(uint4*)vp       = make_uint4(wb[0], wb[1], wb[2], wb[3]);
        *(uint4*)(vp + 8) = make_uint4(wb[4], wb[5], wb[6], wb[7]);
    } else if (jbase >= M){
        *(uint4*)vp       = make_uint4(0, 0, 0, 0);
        *(uint4*)(vp + 8) = make_uint4(0, 0, 0, 0);
    } else {
        for (int jj = 0; jj < 16; ++jj)
            vp[jj] = (jbase + jj < M) ? Tsh[jq * 16 + jj][c] : (bhalf)0;
    }
}

// ================================================================ proj_packed: packed-epilogue projections (no LDS).
// blocks: [0,1280) Qproj | [1280,1920) qkl dual | [1920,2025) Kproj_fg | [2025,2055) Kproj_bg
struct ProjArgs {
    const bhalf *q_in, *ctx_all, *x_la;
    const bhalf *wqobjT, *wkobjT, *wk2T, *lawqT, *wvobjT, *wv2T, *lawvT;
    bhalf *q_obj, *k_obj, *k_bg, *qkl, *vt_obj, *vt_bg, *vt_l;
};

__global__ __launch_bounds__(256) void proj_packed(ProjArgs a){
    const int r = blockIdx.x;
    if (r < 1280)      gemm5_body<320>(r % 256, r / 256, a.q_in, a.wqobjT, a.q_obj, 16384, 4096, K2E);
    else if (r < 1920){ const int s = r - 1280; const int by = s / 64, bx = s % 64;
        gemm5_body<320>(bx, by, a.x_la, a.lawqT, a.qkl, 4096, 4096, by < 5 ? K2E : 1.f); }
    else if (r < 2025){ const int s = r - 1920; gemm5_body<768>(s % 21, s / 21, a.ctx_all, a.wkobjT, a.k_obj, 1344, 336, 1.f); }
    else { const int s = r - 2025; gemm5_body<768>(s % 6, s / 6, a.ctx_all + (size_t)4 * 336 * 768, a.wk2T, a.k_bg, 336, 336, 1.f); }
}

// ================================================================ proj_vt: V-transpose projections.
// blocks: [0,150) Vt fg+bg | [150,470) Vt_l
__global__ __launch_bounds__(256) void proj_vt(ProjArgs a){
    __shared__ bhalf Tsh[64][72];
    const int r = blockIdx.x;
    if (r < 150){ const int bz = r / 30, rem = r % 30;
        if (bz == 4) gemm_vt_body<768>(rem % 6, rem / 6, a.ctx_all + (size_t)4 * 336 * 768, a.wv2T, a.vt_bg, 336, 384, 384, Tsh);
        else gemm_vt_body<768>(rem % 6, rem / 6, a.ctx_all + (size_t)bz * 336 * 768, a.wvobjT, a.vt_obj + (size_t)bz * 320 * 384, 336, 384, 384, Tsh);
    }
    else { const int s = r - 150; gemm_vt_body<320>(s % 64, s / 64, a.x_la, a.lawvT, a.vt_l, 4096, 4096, 4096, Tsh); }
}

// ================================================================ LayerNorm over f32 rows (Sbuf -> q2)
__global__ __launch_bounds__(320) void ln_rows_kernel(
    const float* __restrict__ in, const float* __restrict__ g, const float* __restrict__ b,
    bhalf* __restrict__ out)
{
    const int row = blockIdx.x, c = threadIdx.x;
    const float v = in[(long)row * 320 + c];
    float s = v, sq = v * v;
#pragma unroll
    for (int o = 1; o < 64; o <<= 1){ s += __shfl_xor(s, o); sq += __shfl_xor(sq, o); }
    __shared__ float rs[5], rq[5];
    const int wv = threadIdx.x >> 6;
    if ((threadIdx.x & 63) == 0){ rs[wv] = s; rq[wv] = sq; }
    __syncthreads();
    if (threadIdx.x == 0){
        float ts = 0, tq = 0;
#pragma unroll
        for (int w = 0; w < 5; ++w){ ts += rs[w]; tq += rq[w]; }
        rs[0] = ts; rq[0] = tq;
    }
    __syncthreads();
    const float mean = rs[0] * (1.f / 320.f);
    const float var  = rq[0] * (1.f / 320.f) - mean * mean;
    const float inv  = rsqrtf(var + 1e-5f);
    out[(long)row * 320 + c] = f2bf((v - mean) * inv * g[c] + b[c]);
}

// ================================================================ standalone GEMM (modes 5 / 6 / 8), K=320 compile-time
template<int MODE>
__global__ __launch_bounds__(256) void gemm320(
    const bhalf* __restrict__ A, const bhalf* __restrict__ Wt,
    const float* __restrict__ bias, bhalf* __restrict__ Cbf,
    float* __restrict__ Cf, const float* __restrict__ add1, const float* __restrict__ add2,
    int M, int kdm, float ascale,
    const bhalf* __restrict__ A2, const bhalf* __restrict__ Wt2, const float* __restrict__ bias2)
{
    constexpr int K = 320;
    const int wave = threadIdx.x >> 6, lane = threadIdx.x & 63;
    const int m0 = blockIdx.x * 64 + wave * 16;
    const int n0 = blockIdx.y * 64;
    int mrow = m0 + (lane & 15); if (mrow > M - 1) mrow = M - 1;
    const int klo = (lane >> 4) * 8;
    const bhalf* ap = A + (long)mrow * K + klo;
    const bhalf* wp = Wt + (long)(n0 + (lane & 15)) * K + klo;
    const f32x4 fz = {0.f, 0.f, 0.f, 0.f};
    f32x4 acc[4]; acc[0] = fz; acc[1] = fz; acc[2] = fz; acc[3] = fz;
#pragma unroll
    for (int k0 = 0; k0 < K; k0 += 32){
        s16x8 a = *(const s16x8*)(ap + k0);
#pragma unroll
        for (int t = 0; t < 4; ++t){
            s16x8 b = *(const s16x8*)(wp + (long)t * 16 * K + k0);
            acc[t] = __builtin_amdgcn_mfma_f32_16x16x32_bf16(a, b, acc[t], 0, 0, 0);
        }
    }
    if (MODE == 6){
        const bhalf* ap2 = A2 + (long)mrow * K + klo;
        const bhalf* wp2 = Wt2 + (long)(n0 + (lane & 15)) * K + klo;
#pragma unroll
        for (int k0 = 0; k0 < K; k0 += 32){
            s16x8 a = *(const s16x8*)(ap2 + k0);
#pragma unroll
            for (int t = 0; t < 4; ++t){
                s16x8 b = *(const s16x8*)(wp2 + (long)t * 16 * K + k0);
                acc[t] = __builtin_amdgcn_mfma_f32_16x16x32_bf16(a, b, acc[t], 0, 0, 0);
            }
        }
    }
    if (MODE == 8){
#pragma unroll
        for (int i = 1; i < 4; ++i){
            const bhalf* api = A + (long)i * kdm + (long)mrow * K + klo;
#pragma unroll
            for (int k0 = 0; k0 < K; k0 += 32){
                s16x8 a = *(const s16x8*)(api + k0);
#pragma unroll
                for (int t = 0; t < 4; ++t){
                    s16x8 b = *(const s16x8*)(wp + (long)t * 16 * K + k0);
                    acc[t] = __builtin_amdgcn_mfma_f32_16x16x32_bf16(a, b, acc[t], 0, 0, 0);
                }
            }
        }
    }
    const int rb = m0 + (lane >> 4) * 4;
    int rin[4], rn[4];
    if (MODE == 5){
#pragma unroll
        for (int r = 0; r < 4; ++r){ const int row = rb + r; rin[r] = row / kdm; rn[r] = row % kdm; }
    }
#pragma unroll
    for (int t = 0; t < 4; ++t){
        const int col = n0 + t * 16 + (lane & 15);
        const int hh = col / 40, cc = col % 40;
#pragma unroll
        for (int r = 0; r < 4; ++r){
            const int row = rb + r;
            if (row >= M) continue;
            const float v = acc[t][r];
            if (MODE == 5)
                Cbf[(((long)rin[r] * 8 + hh) * kdm + rn[r]) * 40 + cc] = f2bf(v * ascale);
            else if (MODE == 6){
                const long o = (long)row * 320 + col;
                Cf[o] = v + bias[col] + bias2[col] + add1[o] + add2[o];
            }
            else if (MODE == 8){
                const long o = (long)row * 320 + col;
                float ssum = 0.f, cax = 0.f;
#pragma unroll
                for (int i = 0; i < 4; ++i){
                    const float sg = add2[i * 4096 + row];
                    ssum += sg;
                    cax += sg * add1[(long)i * 4096 * 320 + o];
                }
                Cf[o] = v + ssum * bias[col] + cax;
            }
        }
    }
}

// ================================================================ flash attention v4: fixed-max softmax (m == 0).
// Q pre-scaled by K2E at projection; p = exp2(score). Masked/tail lanes d=NEG_INF -> p = +0.
template<bool GMM, bool PARTIAL, bool SIG>
__global__ __launch_bounds__(256) void flash4(
    const bhalf* __restrict__ Qh, const bhalf* __restrict__ Kh, const bhalf* __restrict__ Vt,
    bhalf* __restrict__ O, const u64* __restrict__ maskb,
    int NKV, long qh_is, long qh_hs, long kh_is, long kh_hs, long vt_is, int vt_ns, long o_is,
    const float* __restrict__ sigp, bhalf* __restrict__ pacc, float* __restrict__ pl)
{
    const int lane = threadIdx.x & 63, wave = threadIdx.x >> 6;
    const int l15 = lane & 15, hi = lane >> 4, klo = hi * 8;
    const int h = blockIdx.y;
    const int inst = PARTIAL ? 0 : blockIdx.z;
    const int g = PARTIAL ? blockIdx.z : 0;
    const int qbase = blockIdx.x * 256 + wave * 64;
    const s16x8 z8 = {0, 0, 0, 0, 0, 0, 0, 0};
    const f32x4 fz = {0.f, 0.f, 0.f, 0.f};

    s16x8 qa0[4], qa1[4];
#pragma unroll
    for (int qg = 0; qg < 4; ++qg){
        const bhalf* qp = Qh + inst * qh_is + h * qh_hs + (long)(qbase + qg * 16 + l15) * 40;
        qa0[qg] = *(const s16x8*)(qp + klo);
        qa1[qg] = (hi == 0) ? *(const s16x8*)(qp + 32) : z8;
    }
    const int krbase = 8 * (l15 >> 2) + (l15 & 3);
    const bhalf* khead = Kh + inst * kh_is + h * kh_hs;
    const bhalf* kbase = khead + (long)krbase * 40;

    const bhalf* vbase[3];
#pragma unroll
    for (int ct = 0; ct < 3; ++ct){
        int dr = h * 40 + ct * 16 + l15; if (dr > 319) dr = 319;
        vbase[ct] = Vt + inst * vt_is + (long)dr * vt_ns + hi * 8;
    }

    f32x4 acc[4][3];
    float l_run[4];
#pragma unroll
    for (int qg = 0; qg < 4; ++qg){
        acc[qg][0] = fz; acc[qg][1] = fz; acc[qg][2] = fz;
        l_run[qg] = 0.f;
    }

    auto soft_pv = [&](f32x4 (&d)[4], s16x8 (&vb)[3][2], float& lr, f32x4 (&ac)[3]){
        float csum = 0.f;
#pragma unroll
        for (int t = 0; t < 4; ++t)
#pragma unroll
            for (int r = 0; r < 4; ++r){
                const float p = fexp2(d[t][r]);
                d[t][r] = p; csum += p;
            }
        csum += __shfl_xor(csum, 16);
        csum += __shfl_xor(csum, 32);
        lr += csum;
#pragma unroll
        for (int s = 0; s < 2; ++s){
            union { u32 w[4]; s16x8 v; } pb;
            pb.w[0] = cvtpk(d[2 * s][0], d[2 * s][1]);
            pb.w[1] = cvtpk(d[2 * s][2], d[2 * s][3]);
            pb.w[2] = cvtpk(d[2 * s + 1][0], d[2 * s + 1][1]);
            pb.w[3] = cvtpk(d[2 * s + 1][2], d[2 * s + 1][3]);
#pragma unroll
            for (int ct = 0; ct < 3; ++ct)
                ac[ct] = __builtin_amdgcn_mfma_f32_16x16x32_bf16(vb[ct][s], pb.v, ac[ct], 0, 0, 0);
        }
    };

    const int ch0 = PARTIAL ? g * 8 : 0;
    const int chN = PARTIAL ? ch0 + 8 : (NKV >> 6);
    for (int ch = ch0; ch < chN; ++ch){
        const int c0 = ch << 6;
        s16x8 k0[4], k1[4];
#pragma unroll
        for (int t = 0; t < 4; ++t){
            const int toff = ((t >> 1) << 5) + ((t & 1) << 2);
            const bhalf* kp = kbase + (long)(c0 + toff) * 40;
            k0[t] = *(const s16x8*)(kp + klo);
            k1[t] = (hi == 0) ? *(const s16x8*)(kp + 32) : z8;
        }
        s16x8 vb[3][2];
#pragma unroll
        for (int ct = 0; ct < 3; ++ct)
#pragma unroll
            for (int s = 0; s < 2; ++s)
                vb[ct][s] = *(const s16x8*)(vbase[ct] + c0 + 32 * s);
        u64 M[4];
        if (GMM){
#pragma unroll
            for (int qg = 0; qg < 4; ++qg)
                M[qg] = maskb[(long)ch * 4096 + qbase + qg * 16 + l15];
        }
#pragma unroll
        for (int qg = 0; qg < 4; ++qg){
            f32x4 d[4];
#pragma unroll
            for (int t = 0; t < 4; ++t){
                d[t] = __builtin_amdgcn_mfma_f32_16x16x32_bf16(k0[t], qa0[qg], fz, 0, 0, 0);
                d[t] = __builtin_amdgcn_mfma_f32_16x16x32_bf16(k1[t], qa1[qg], d[t], 0, 0, 0);
            }
            if (GMM && !__all(M[qg] == ~0ull)){
                const u64 Mh = M[qg] >> (hi * 8);
#pragma unroll
                for (int t = 0; t < 4; ++t){
                    const int tb = ((t >> 1) << 5) + ((t & 1) << 2);
#pragma unroll
                    for (int r = 0; r < 4; ++r)
                        if (!((Mh >> (tb + r)) & 1)) d[t][r] = NEG_INF;
                }
            }
            soft_pv(d, vb, l_run[qg], acc[qg]);
        }
    }
    if (!PARTIAL && (NKV & 63)){
        const int c0 = (NKV >> 6) << 6;
        s16x8 k0[4], k1[4];
#pragma unroll
        for (int t = 0; t < 4; ++t){
            const int toff = ((t >> 1) << 5) + ((t & 1) << 2);
            int kr = c0 + toff + krbase; if (kr > NKV - 1) kr = NKV - 1;
            const bhalf* kp = khead + (long)kr * 40;
            k0[t] = *(const s16x8*)(kp + klo);
            k1[t] = (hi == 0) ? *(const s16x8*)(kp + 32) : z8;
        }
        s16x8 vb[3][2];
#pragma unroll
        for (int ct = 0; ct < 3; ++ct)
#pragma unroll
            for (int s = 0; s < 2; ++s)
                vb[ct][s] = *(const s16x8*)(vbase[ct] + c0 + 32 * s);
#pragma unroll
        for (int qg = 0; qg < 4; ++qg){
            f32x4 d[4];
#pragma unroll
            for (int t = 0; t < 4; ++t){
                d[t] = __builtin_amdgcn_mfma_f32_16x16x32_bf16(k0[t], qa0[qg], fz, 0, 0, 0);
                d[t] = __builtin_amdgcn_mfma_f32_16x16x32_bf16(k1[t], qa1[qg], d[t], 0, 0, 0);
            }
#pragma unroll
            for (int t = 0; t < 4; ++t){
                const int tb = ((t >> 1) << 5) + ((t & 1) << 2);
#pragma unroll
                for (int r = 0; r < 4; ++r)
                    if (c0 + tb + hi * 8 + r >= NKV) d[t][r] = NEG_INF;
            }
            soft_pv(d, vb, l_run[qg], acc[qg]);
        }
    }

    if (PARTIAL){
#pragma unroll
        for (int qg = 0; qg < 4; ++qg){
            const int q = qbase + qg * 16 + l15;
#pragma unroll
            for (int ct = 0; ct < 3; ++ct){
                bhalf* pb = pacc + ((((size_t)(g * 8 + h) * 3 + ct) * 4 + hi) * 4096 + q) * 4;
                uint2 w;
                w.x = cvtpk(acc[qg][ct][0], acc[qg][ct][1]);
                w.y = cvtpk(acc[qg][ct][2], acc[qg][ct][3]);
                *(uint2*)pb = w;
            }
            if (hi == 0)
                pl[(size_t)(g * 8 + h) * 4096 + q] = l_run[qg];
        }
    } else {
#pragma unroll
        for (int qg = 0; qg < 4; ++qg){
            const int q = qbase + qg * 16 + l15;
            float sc = 1.f / l_run[qg];
            if (SIG) sc *= sigp[(long)inst * 4096 + q];
            bhalf* op = O + inst * o_is + (long)q * 320 + h * 40;
#pragma unroll
            for (int ct = 0; ct < 3; ++ct){
                const int d0 = ct * 16 + hi * 4;
                if (d0 < 40){
                    uint2 w;
                    w.x = cvtpk(acc[qg][ct][0] * sc, acc[qg][ct][1] * sc);
                    w.y = cvtpk(acc[qg][ct][2] * sc, acc[qg][ct][3] * sc);
                    *(uint2*)(op + d0) = w;
                }
            }
        }
    }
}

// ================================================================ combine kv-split partials (fixed-max: plain sums)
__global__ __launch_bounds__(256) void combine_kernel(
    const bhalf* __restrict__ pacc, const float* __restrict__ pl, bhalf* __restrict__ O)
{
    const int idx = blockIdx.x * 256 + threadIdx.x;
    const int h = idx / (3 * 4096);
    const int r2 = idx % (3 * 4096);
    const int ct = r2 >> 12, q = r2 & 4095;
    float ls = 0.f;
#pragma unroll
    for (int g = 0; g < 8; ++g) ls += pl[(size_t)(g * 8 + h) * 4096 + q];
    float acc[16];
#pragma unroll
    for (int d = 0; d < 16; ++d) acc[d] = 0.f;
#pragma unroll
    for (int g = 0; g < 8; ++g){
#pragma unroll
        for (int hi = 0; hi < 4; ++hi){
            const ushort4 v = *(const ushort4*)(pacc + ((((size_t)(g * 8 + h) * 3 + ct) * 4 + hi) * 4096 + q) * 4);
            acc[hi * 4 + 0] += bf2f(v.x);
            acc[hi * 4 + 1] += bf2f(v.y);
            acc[hi * 4 + 2] += bf2f(v.z);
            acc[hi * 4 + 3] += bf2f(v.w);
        }
    }
    const float inv = 1.f / ls;
    bhalf* op = O + (size_t)q * 320 + h * 40 + ct * 16;
    if (ct < 2){
        u32 wb[8];
#pragma unroll
        for (int d = 0; d < 8; ++d) wb[d] = cvtpk(acc[2 * d] * inv, acc[2 * d + 1] * inv);
        *(uint4*)op       = make_uint4(wb[0], wb[1], wb[2], wb[3]);
        *(uint4*)(op + 8) = make_uint4(wb[4], wb[5], wb[6], wb[7]);
    } else {
        u32 wb[4];
#pragma unroll
        for (int d = 0; d < 4; ++d) wb[d] = cvtpk(acc[2 * d] * inv, acc[2 * d + 1] * inv);
        *(uint4*)op = make_uint4(wb[0], wb[1], wb[2], wb[3]);
    }
}

// ================================================================ host
extern "C" void kernel_launch(void* const* d_in, const int* in_sizes, int n_in,
                              void* d_out, int out_size, void* d_ws, size_t ws_size,
                              hipStream_t stream)
{
    (void)in_sizes; (void)n_in; (void)out_size; (void)ws_size;
    const float* ca_x   = (const float*)d_in[0];
    const float* gmask  = (const float*)d_in[1];
    const float* smask  = (const float*)d_in[2];
    const float* itok   = (const float*)d_in[3];
    const float* ctx    = (const float*)d_in[4];
    const float* box    = (const float*)d_in[5];
    const float* imgf   = (const float*)d_in[6];
    const float* bgf    = (const float*)d_in[7];
    const float* sgv    = (const float*)d_in[8];
    const float* Wq_obj = (const float*)d_in[9];
    const float* Wk_obj = (const float*)d_in[10];
    const float* Wv_obj = (const float*)d_in[11];
    const float* Wo_obj = (const float*)d_in[12];
    const float* bo_obj = (const float*)d_in[13];
    const float* g_obj  = (const float*)d_in[14];
    const float* b_obj  = (const float*)d_in[15];
    const float* Wq2    = (const float*)d_in[16];
    const float* Wk2    = (const float*)d_in[17];
    const float* Wv2    = (const float*)d_in[18];
    const float* Wo2    = (const float*)d_in[19];
    const float* bo2    = (const float*)d_in[20];
    const float* g2     = (const float*)d_in[21];
    const float* b2     = (const float*)d_in[22];
    const float* pnW1   = (const float*)d_in[23];
    const float* pnb1   = (const float*)d_in[24];
    const float* pnW2   = (const float*)d_in[25];
    const float* pnb2   = (const float*)d_in[26];
    const float* pnW3   = (const float*)d_in[27];
    const float* pnb3   = (const float*)d_in[28];
    const float* laWq   = (const float*)d_in[29];
    const float* laWk   = (const float*)d_in[30];
    const float* laWv   = (const float*)d_in[31];
    const float* laWo   = (const float*)d_in[32];
    const float* labo   = (const float*)d_in[33];

    char* wsp = (char*)d_ws; size_t off = 0;
    auto alloc = [&](size_t bytes) -> void* {
        void* p = wsp + off; off += (bytes + 255) & ~(size_t)255; return p;
    };
    bhalf* wqobjT = (bhalf*)alloc(320 * 320 * 2);
    bhalf* woobjT = (bhalf*)alloc(320 * 320 * 2);
    bhalf* wq2T   = (bhalf*)alloc(320 * 320 * 2);
    bhalf* wo2T   = (bhalf*)alloc(320 * 320 * 2);
    bhalf* lawqT  = (bhalf*)alloc(320 * 320 * 2);   // lawqT..lawkT contiguous (204800 % 256 == 0)
    bhalf* lawkT  = (bhalf*)alloc(320 * 320 * 2);
    bhalf* lawvT  = (bhalf*)alloc(320 * 320 * 2);
    bhalf* lawoT  = (bhalf*)alloc(320 * 320 * 2);
    bhalf* wkobjT = (bhalf*)alloc(768 * 320 * 2);
    bhalf* wvobjT = (bhalf*)alloc(768 * 320 * 2);
    bhalf* wk2T   = (bhalf*)alloc(768 * 320 * 2);
    bhalf* wv2T   = (bhalf*)alloc(768 * 320 * 2);
    float* gm_all = (float*)alloc(5 * 4096 * 4);
    float* sig    = (float*)alloc(4 * 4096 * 4);
    float* boxtok = (float*)alloc(4 * 768 * 4);
    u64*   maskb  = (u64*)alloc((size_t)64 * 4096 * 8);
    bhalf* ctx_all= (bhalf*)alloc((size_t)5 * 336 * 768 * 2);   // fg[4] then bg
    bhalf* q_in   = (bhalf*)alloc((size_t)16384 * 320 * 2);
    bhalf* x_la   = (bhalf*)alloc((size_t)4096 * 320 * 2);
    bhalf* k_obj  = (bhalf*)alloc((size_t)4 * 336 * 320 * 2);   // packed [4][8][336][40]
    bhalf* vt_obj = (bhalf*)alloc((size_t)4 * 320 * 384 * 2);
    bhalf* k_bg   = (bhalf*)alloc((size_t)336 * 320 * 2);       // packed [8][336][40]
    bhalf* vt_bg  = (bhalf*)alloc((size_t)320 * 384 * 2);
    bhalf* q_obj  = (bhalf*)alloc((size_t)16384 * 320 * 2);     // packed [4][8][4096][40], pre-scaled by K2E
    bhalf* o_obj  = (bhalf*)alloc((size_t)16384 * 320 * 2);     // sig-prescaled attention out
    float* Sbuf   = (float*)alloc((size_t)4096 * 320 * 4);
    bhalf* q2v    = (bhalf*)alloc((size_t)4096 * 320 * 2);
    bhalf* q2p    = (bhalf*)alloc((size_t)4096 * 320 * 2);      // packed [8][4096][40], pre-scaled
    bhalf* o2     = (bhalf*)alloc((size_t)4096 * 320 * 2);
    bhalf* qkl    = (bhalf*)alloc((size_t)2 * 4096 * 320 * 2);  // packed [16][4096][40]: q(pre-scaled) 0-7, k 8-15
    bhalf* vt_l   = (bhalf*)alloc((size_t)320 * 4096 * 2);
    bhalf* ol     = (bhalf*)alloc((size_t)4096 * 320 * 2);

    // kv-split partials alias the dead q_in..o_obj region (36.4 MB; pacc bf16 25.2 + pl 1 = 26.2 MB).
    bhalf* pacc = (bhalf*)q_in;                                       // [8g][8h][3ct][4hi][4096q][4] bf16
    float* pl   = (float*)(pacc + (size_t)8 * 8 * 3 * 4 * 4096 * 4);  // [8g*8h][4096] f32

    // ---- launch 1: mega_prep (posnet x16 | weight transpose | resize | LN + x_la copy)
    PrepArgs pa{};
    pa.itok = itok; pa.g_obj = g_obj; pa.b_obj = b_obj; pa.q_in = q_in; pa.x_la = x_la;
    pa.wt.in[0] = Wq_obj; pa.wt.out[0] = wqobjT;
    pa.wt.in[1] = Wo_obj; pa.wt.out[1] = woobjT;
    pa.wt.in[2] = Wq2;    pa.wt.out[2] = wq2T;
    pa.wt.in[3] = Wo2;    pa.wt.out[3] = wo2T;
    pa.wt.in[4] = laWq;   pa.wt.out[4] = lawqT;
    pa.wt.in[5] = laWk;   pa.wt.out[5] = lawkT;
    pa.wt.in[6] = laWv;   pa.wt.out[6] = lawvT;
    pa.wt.in[7] = laWo;   pa.wt.out[7] = lawoT;
    pa.wt.in[8] = Wk_obj; pa.wt.out[8] = wkobjT;
    pa.wt.in[9] = Wv_obj; pa.wt.out[9] = wvobjT;
    pa.wt.in[10] = Wk2;   pa.wt.out[10] = wk2T;
    pa.wt.in[11] = Wv2;   pa.wt.out[11] = wv2T;
    pa.gmask = gmask; pa.smask = smask; pa.sgv = sgv; pa.gm_all = gm_all; pa.sig = sig;
    pa.box = box; pa.W1 = pnW1; pa.b1 = pnb1; pa.W2 = pnW2; pa.b2 = pnb2; pa.W3 = pnW3; pa.b3 = pnb3;
    pa.tok = boxtok;
    mega_prep<<<dim3(21080), 320, 0, stream>>>(pa);

    // ---- launch 2: mega_mask (maskbits | context assembly)
    mega_mask<<<dim3(5296), 256, 0, stream>>>(gm_all, maskb, ctx, imgf, bgf, boxtok, ctx_all);

    // ---- launch 3+4: projections, split for attribution (packed GEMMs | V-transpose GEMMs)
    ProjArgs pj{};
    pj.q_in = q_in; pj.ctx_all = ctx_all; pj.x_la = x_la;
    pj.wqobjT = wqobjT; pj.wkobjT = wkobjT; pj.wk2T = wk2T; pj.lawqT = lawqT;
    pj.wvobjT = wvobjT; pj.wv2T = wv2T; pj.lawvT = lawvT;
    pj.q_obj = q_obj; pj.k_obj = k_obj; pj.k_bg = k_bg; pj.qkl = qkl;
    pj.vt_obj = vt_obj; pj.vt_bg = vt_bg; pj.vt_l = vt_l;
    proj_packed<<<dim3(2055), 256, 0, stream>>>(pj);
    proj_vt<<<dim3(470), 256, 0, stream>>>(pj);

    // ---- launch 5: ea_obj attention (epilogue x sig)
    flash4<false, false, true><<<dim3(16, 8, 4), 256, 0, stream>>>(q_obj, k_obj, vt_obj, o_obj, nullptr,
        335, (long)8 * 4096 * 40, (long)4096 * 40, (long)8 * 336 * 40, (long)336 * 40,
        (long)320 * 384, 384, (long)4096 * 320, sig, nullptr, nullptr);

    // ---- launch 6: quad O-proj -> Sbuf (+sig*ca_x + sig_sum*bo)
    gemm320<8><<<dim3(64, 5), 256, 0, stream>>>(o_obj, woobjT, bo_obj, nullptr, Sbuf,
        ca_x + (size_t)4096 * 320, sig, 4096, 4096 * 320, 1.f, nullptr, nullptr, nullptr);

    // ---- launch 7: q2 = LN(Sbuf)
    ln_rows_kernel<<<dim3(4096), 320, 0, stream>>>(Sbuf, g2, b2, q2v);

    // ---- launch 8: q2 projection (pre-scaled by K2E)
    gemm320<5><<<dim3(64, 5), 256, 0, stream>>>(q2v, wq2T, nullptr, q2p, nullptr, nullptr, nullptr,
        4096, 4096, K2E, nullptr, nullptr, nullptr);

    // ---- launch 9: ea2 (background) attention
    flash4<false, false, false><<<dim3(16, 8, 1), 256, 0, stream>>>(q2p, k_bg, vt_bg, o2, nullptr,
        334, 0, (long)4096 * 40, 0, (long)336 * 40, 0, 384, 0, nullptr, nullptr, nullptr);

    // ---- launch 10: layout self-attention, kv-split G=8 (partials alias dead region)
    flash4<true, true, false><<<dim3(16, 8, 8), 256, 0, stream>>>(qkl, qkl + (size_t)8 * 4096 * 40, vt_l, nullptr, maskb,
        4096, 0, (long)4096 * 40, 0, (long)4096 * 40, 0, 4096, 0, nullptr, pacc, pl);

    // ---- launch 11: combine partials -> ol
    combine_kernel<<<dim3(384), 256, 0, stream>>>(pacc, pl, ol);

    // ---- launch 12: out = ca_x[0] + S + (o2@Wo2 + bo2) + (ol@laWo + labo)
    gemm320<6><<<dim3(64, 5), 256, 0, stream>>>(o2, wo2T, bo2, nullptr, (float*)d_out, ca_x, Sbuf,
        4096, 1, 1.f, ol, lawoT, labo);
}

// Round 14
// 321.559 us; speedup vs baseline: 1.0304x; 1.0304x over previous
//
#include <hip/hip_runtime.h>
#include <hip/hip_bf16.h>
#include <math.h>

typedef unsigned short bhalf;
typedef unsigned int u32;
typedef unsigned long long u64;
typedef __attribute__((ext_vector_type(8))) short s16x8;
typedef __attribute__((ext_vector_type(4))) float f32x4;

#define SCALE_QK 0.15811388300841898f
#define K2E (SCALE_QK * 1.4426950408889634f)
#define NEG_INF (-3.402823466e38f)

__device__ __forceinline__ float bf2f(bhalf u){
    union { unsigned int i; float f; } v; v.i = ((unsigned int)u) << 16; return v.f;
}
__device__ __forceinline__ bhalf f2bf(float f){
    unsigned int x = __float_as_uint(f);
    unsigned int r = (x + 0x7fffu + ((x >> 16) & 1u)) >> 16;
    return (bhalf)r;
}
__device__ __forceinline__ float fexp2(float x){
    float r; asm("v_exp_f32 %0, %1" : "=v"(r) : "v"(x)); return r;
}
__device__ __forceinline__ u32 cvtpk(float lo, float hi){
    u32 r; asm("v_cvt_pk_bf16_f32 %0, %1, %2" : "=v"(r) : "v"(lo), "v"(hi)); return r;
}

struct WT12 { const float* in[12]; bhalf* out[12]; };

// ================================================================ mega_prep: posnet | transpose | resize | LN (wave/row)
// blocks: [0,16) posnet, [16,456) transpose, [456,600) resize, [600,2648) LN+copy grid-stride. 320 threads.
struct PrepArgs {
    const float *itok, *g_obj, *b_obj; bhalf *q_in, *x_la;
    WT12 wt;
    const float *gmask, *smask, *sgv; float *gm_all, *sig;
    const float *box, *W1, *b1, *W2, *b2, *W3, *b3; float* tok;
};

__global__ __launch_bounds__(320) void mega_prep(PrepArgs a){
    __shared__ float smem[64 * 65];
    const int bid = blockIdx.x, tid = threadIdx.x;
    if (bid < 16){
        // ---- PositionNet: 4 blocks per box, layer-3 sliced 4 ways.
        float* emb = smem; float* h1 = smem + 128; float* h2 = smem + 640;
        const int bb = bid >> 2, sl = bid & 3;
        for (int t = tid; t < 128; t += 320){
            const int i = t >> 4, jj = t & 15, j = jj & 7;
            const float f = powf(100.f, (float)i * 0.125f);
            const float v = f * a.box[bb * 8 + j];
            emb[t] = (jj < 8) ? sinf(v) : cosf(v);
        }
        __syncthreads();
        for (int t = tid; t < 512; t += 320){
            float a0 = a.b1[t], a1 = 0.f, a2 = 0.f, a3 = 0.f;
#pragma unroll 8
            for (int k = 0; k < 32; ++k){
                a0 += emb[k]      * a.W1[k * 512 + t];
                a1 += emb[k + 32] * a.W1[(k + 32) * 512 + t];
                a2 += emb[k + 64] * a.W1[(k + 64) * 512 + t];
                a3 += emb[k + 96] * a.W1[(k + 96) * 512 + t];
            }
            const float x = (a0 + a1) + (a2 + a3);
            h1[t] = x / (1.f + __expf(-x));
        }
        __syncthreads();
        for (int t = tid; t < 512; t += 320){
            float a0 = a.b2[t], a1 = 0.f, a2 = 0.f, a3 = 0.f;
#pragma unroll 8
            for (int k = 0; k < 128; ++k){
                a0 += h1[k]       * a.W2[k * 512 + t];
                a1 += h1[k + 128] * a.W2[(k + 128) * 512 + t];
                a2 += h1[k + 256] * a.W2[(k + 256) * 512 + t];
                a3 += h1[k + 384] * a.W2[(k + 384) * 512 + t];
            }
            const float x = (a0 + a1) + (a2 + a3);
            h2[t] = x / (1.f + __expf(-x));
        }
        __syncthreads();
        if (tid < 192){
            const int t = sl * 192 + tid;
            float a0 = a.b3[t], a1 = 0.f, a2 = 0.f, a3 = 0.f;
#pragma unroll 8
            for (int k = 0; k < 128; ++k){
                a0 += h2[k]       * a.W3[k * 768 + t];
                a1 += h2[k + 128] * a.W3[(k + 128) * 768 + t];
                a2 += h2[k + 256] * a.W3[(k + 256) * 768 + t];
                a3 += h2[k + 384] * a.W3[(k + 384) * 768 + t];
            }
            a.tok[bb * 768 + t] = (a0 + a1) + (a2 + a3);
        }
    } else if (bid < 456){
        // ---- weight transpose (LDS-tiled), b = bid-16
        float (*T)[65] = (float(*)[65])smem;
        const int b = bid - 16;
        int w, t, K;
        if (b < 200){ w = b / 25; t = b % 25; K = 320; }
        else        { w = 8 + (b - 200) / 60; t = (b - 200) % 60; K = 768; }
        const int k0 = (t / 5) * 64, n0 = (t % 5) * 64;
        const float* in = a.wt.in[w];
        bhalf* out = a.wt.out[w];
        const int c = tid & 63, wv = tid >> 6;
        if (tid < 256){
#pragma unroll
            for (int r = 0; r < 16; ++r)
                T[wv + r * 4][c] = in[(long)(k0 + wv + r * 4) * 320 + n0 + c];
        }
        __syncthreads();
        if (tid < 256){
#pragma unroll
            for (int r = 0; r < 16; ++r)
                out[(long)(n0 + wv + r * 4) * K + k0 + c] = f2bf(T[c][wv + r * 4]);
        }
    } else if (bid < 600){
        // ---- resize (8x down, 4-tap avg), b = bid-456
        if (tid < 256){
            const int b = bid - 456;
            const int p = b >> 4;
            const int i = (b & 15) * 256 + tid;
            const int y = i >> 6, x = i & 63;
            const int o = (8 * y + 3) * 512 + 8 * x + 3;
            const float* s; float* dst;
            if (p < 4){ s = a.gmask + (long)p * 262144; dst = a.gm_all + p * 4096; }
            else if (p == 4){ s = a.smask; dst = a.gm_all + 4 * 4096; }
            else { s = a.sgv + (long)(p - 5) * 262144; dst = a.sig + (p - 5) * 4096; }
            dst[i] = 0.25f * (s[o] + s[o + 1] + s[o + 512] + s[o + 513]);
        }
    } else {
        // ---- LN wave-per-row, grid-stride, no barriers (20480 tiny blocks was block-throughput-bound)
        const int lane = tid & 63, wv = tid >> 6;
        const int wgid = (bid - 600) * 5 + wv;        // 2048 blocks x 5 waves = 10240 waves
        for (int row = wgid; row < 20480; row += 10240){
            if (row >= 16384){
                const int rr = row - 16384;
#pragma unroll
                for (int j = 0; j < 5; ++j){
                    const int c = lane + 64 * j;
                    a.x_la[(long)rr * 320 + c] = f2bf(a.itok[(long)rr * 320 + c]);
                }
                continue;
            }
            float v[5];
            float s = 0.f, sq = 0.f;
#pragma unroll
            for (int j = 0; j < 5; ++j){
                v[j] = a.itok[(long)(4096 + row) * 320 + lane + 64 * j];
                s += v[j]; sq += v[j] * v[j];
            }
#pragma unroll
            for (int o = 1; o < 64; o <<= 1){ s += __shfl_xor(s, o); sq += __shfl_xor(sq, o); }
            const float mean = s * (1.f / 320.f);
            const float var  = sq * (1.f / 320.f) - mean * mean;
            const float inv  = rsqrtf(var + 1e-5f);
#pragma unroll
            for (int j = 0; j < 5; ++j){
                const int c = lane + 64 * j;
                a.q_in[(long)row * 320 + c] = f2bf((v[j] - mean) * inv * a.g_obj[c] + a.b_obj[c]);
            }
        }
    }
}

// ================================================================ mega_mask: maskbits | assemble. 256 threads.
__global__ __launch_bounds__(256) void mega_mask(
    const float* __restrict__ gm_all, u64* __restrict__ mb,
    const float* __restrict__ context, const float* __restrict__ imgf,
    const float* __restrict__ bgf, const float* __restrict__ boxtok, bhalf* __restrict__ out)
{
    __shared__ float smem[5440];
    const int tid = threadIdx.x;
    if (blockIdx.x < 256){
        const int r = blockIdx.x;
        const int i0 = (r & 63) << 6, j0 = (r >> 6) << 10;
        float* gi = smem;          // [5][64]
        float* gj = smem + 320;    // [5][1024]
        for (int idx = tid; idx < 5 * 64; idx += 256)
            gi[idx] = gm_all[(idx >> 6) * 4096 + i0 + (idx & 63)];
        for (int idx = tid; idx < 5 * 1024; idx += 256)
            gj[idx] = gm_all[(idx >> 10) * 4096 + j0 + (idx & 1023)];
        __syncthreads();
        const int lane = tid & 63, wave = tid >> 6;
        const float a0 = gi[lane], a1 = gi[64 + lane], a2 = gi[128 + lane],
                    a3 = gi[192 + lane], a4 = gi[256 + lane];
        for (int ww = wave; ww < 16; ww += 4){
            u64 m = 0;
            for (int j = 0; j < 64; ++j){
                const int jj = (ww << 6) + j;
                const float dot = a0 * gj[jj] + a1 * gj[1024 + jj] + a2 * gj[2048 + jj]
                                + a3 * gj[3072 + jj] + a4 * gj[4096 + jj];
                m |= (u64)(dot != 0.f) << j;
            }
            mb[(long)((j0 >> 6) + ww) * 4096 + (i0 + lane)] = m;
        }
    } else {
        const int idx = (blockIdx.x - 256) * 256 + tid;
        const int i = idx / (336 * 768);
        const int r = (idx / 768) % 336;
        const int c = idx % 768;
        float v;
        if (i < 4){
            if (r < 77)       v = context[((long)(1 + i) * 77 + r) * 768 + c];
            else if (r < 334) v = imgf[((long)i * 257 + (r - 77)) * 768 + c];
            else if (r == 334) v = boxtok[i * 768 + c];
            else v = 0.f;
        } else {
            if (r < 77)       v = context[(long)r * 768 + c];
            else if (r < 334) v = bgf[(long)(r - 77) * 768 + c];
            else v = 0.f;
        }
        out[idx] = f2bf(v);
    }
}

// ================================================================ gemm5x4: wave computes 64 rows x 64 cols
// (4 m-frags share each B-frag: 128 cache-lines per 4 tiles vs 80 per 1 -> 2.5x fewer line lookups;
//  r11-r13 showed ILP tweaks are null: the per-CU miss-queue is the limit, so cut lines per work)
template<int K>
__device__ __forceinline__ void gemm5x4_body(
    int bx, int by, const bhalf* __restrict__ A, const bhalf* __restrict__ Wt,
    bhalf* __restrict__ Cbf, int M, int kdm, float scale)
{
    const int wave = threadIdx.x >> 6, lane = threadIdx.x & 63;
    const int mb = bx * 256 + wave * 64;
    const int n0 = by * 64;
    const int klo = (lane >> 4) * 8;
    const bhalf* ap[4];
#pragma unroll
    for (int f = 0; f < 4; ++f){
        int mrow = mb + f * 16 + (lane & 15); if (mrow > M - 1) mrow = M - 1;
        ap[f] = A + (long)mrow * K + klo;
    }
    const bhalf* wp = Wt + (long)(n0 + (lane & 15)) * K + klo;
    const f32x4 fz = {0.f, 0.f, 0.f, 0.f};
    f32x4 acc[4][4];
#pragma unroll
    for (int f = 0; f < 4; ++f)
#pragma unroll
        for (int t = 0; t < 4; ++t) acc[f][t] = fz;
#pragma unroll
    for (int k0 = 0; k0 < K; k0 += 32){
        s16x8 av[4];
#pragma unroll
        for (int f = 0; f < 4; ++f) av[f] = *(const s16x8*)(ap[f] + k0);
        s16x8 bv[4];
#pragma unroll
        for (int t = 0; t < 4; ++t) bv[t] = *(const s16x8*)(wp + (long)t * 16 * K + k0);
#pragma unroll
        for (int f = 0; f < 4; ++f)
#pragma unroll
            for (int t = 0; t < 4; ++t)
                acc[f][t] = __builtin_amdgcn_mfma_f32_16x16x32_bf16(av[f], bv[t], acc[f][t], 0, 0, 0);
    }
#pragma unroll
    for (int f = 0; f < 4; ++f){
        const int rb = mb + f * 16 + ((threadIdx.x & 63) >> 4) * 4;
#pragma unroll
        for (int t = 0; t < 4; ++t){
            const int col = n0 + t * 16 + (threadIdx.x & 15);
            const int hh = col / 40, cc = col % 40;
#pragma unroll
            for (int r = 0; r < 4; ++r){
                const int row = rb + r;
                if (row >= M) continue;
                Cbf[(((long)(row / kdm) * 8 + hh) * kdm + (row % kdm)) * 40 + cc] = f2bf(acc[f][t][r] * scale);
            }
        }
    }
}

template<int K>
__device__ __forceinline__ void gemm_vt_body(
    int bx, int by, const bhalf* __restrict__ A, const bhalf* __restrict__ Wt,
    bhalf* __restrict__ Vt, int M, int vt_ns, int PAD, bhalf (*Tsh)[72])
{
    const int wave = threadIdx.x >> 6, lane = threadIdx.x & 63;
    const int m0 = bx * 64 + wave * 16;
    const int n0 = by * 64;
    int mrow = m0 + (lane & 15); if (mrow > M - 1) mrow = M - 1;
    const int klo = (lane >> 4) * 8;
    const bhalf* ap = A + (long)mrow * K + klo;
    const bhalf* wp = Wt + (long)(n0 + (lane & 15)) * K + klo;
    const f32x4 fz = {0.f, 0.f, 0.f, 0.f};
    f32x4 acc[4]; acc[0] = fz; acc[1] = fz; acc[2] = fz; acc[3] = fz;
#pragma unroll
    for (int k0 = 0; k0 < K; k0 += 32){
        s16x8 a = *(const s16x8*)(ap + k0);
#pragma unroll
        for (int t = 0; t < 4; ++t){
            s16x8 b = *(const s16x8*)(wp + (long)t * 16 * K + k0);
            acc[t] = __builtin_amdgcn_mfma_f32_16x16x32_bf16(a, b, acc[t], 0, 0, 0);
        }
    }
    const int hi = lane >> 4, l15 = lane & 15;
#pragma unroll
    for (int t = 0; t < 4; ++t)
#pragma unroll
        for (int r = 0; r < 4; ++r)
            Tsh[wave * 16 + hi * 4 + r][t * 16 + l15] = f2bf(acc[t][r]);
    __syncthreads();
    const int c = threadIdx.x & 63, jq = threadIdx.x >> 6;
    const int jbase = bx * 64 + jq * 16;
    if (jbase >= PAD) return;
    bhalf* vp = Vt + (long)(n0 + c) * vt_ns + jbase;
    if (jbase + 16 <= M){
        u32 wb[8];
#pragma unroll
        for (int p = 0; p < 8; ++p)
            wb[p] = (u32)Tsh[jq * 16 + 2 * p][c] | ((u32)Tsh[jq * 16 + 2 * p + 1][c] << 16);
        *(uint4*)vp       = make_uint4(wb[0], wb[1], wb[2], wb[3]);
        *(uint4*)(vp + 8) = make_uint4(wb[4], wb[5], wb[6], wb[7]);
    } else if (jbase >= M){
        *(uint4*)vp       = make_uint4(0, 0, 0, 0);
        *(uint4*)(vp + 8) = make_uint4(0, 0, 0, 0);
    } else {
        for (int jj = 0; jj < 16; ++jj)
            vp[jj] = (jbase + jj < M) ? Tsh[jq * 16 + jj][c] : (bhalf)0;
    }
}

// ================================================================ proj_packed: packed-epilogue projections, 64x64/wave.
// blocks: [0,320) Qproj | [320,480) qkl dual | [480,510) Kproj_fg | [510,520) Kproj_bg
struct ProjArgs {
    const bhalf *q_in, *ctx_all, *x_la;
    const bhalf *wqobjT, *wkobjT, *wk2T, *lawqT, *wvobjT, *wv2T, *lawvT;
    bhalf *q_obj, *k_obj, *k_bg, *qkl, *vt_obj, *vt_bg, *vt_l;
};

__global__ __launch_bounds__(256) void proj_packed(ProjArgs a){
    const int r = blockIdx.x;
    if (r < 320)       gemm5x4_body<320>(r % 64, r / 64, a.q_in, a.wqobjT, a.q_obj, 16384, 4096, K2E);
    else if (r < 480){ const int s = r - 320; const int by = s / 16, bx = s % 16;
        gemm5x4_body<320>(bx, by, a.x_la, a.lawqT, a.qkl, 4096, 4096, by < 5 ? K2E : 1.f); }
    else if (r < 510){ const int s = r - 480; gemm5x4_body<768>(s % 6, s / 6, a.ctx_all, a.wkobjT, a.k_obj, 1344, 336, 1.f); }
    else { const int s = r - 510; gemm5x4_body<768>(s % 2, s / 2, a.ctx_all + (size_t)4 * 336 * 768, a.wk2T, a.k_bg, 336, 336, 1.f); }
}

// ================================================================ proj_vt: V-transpose projections.
// blocks: [0,150) Vt fg+bg | [150,470) Vt_l
__global__ __launch_bounds__(256) void proj_vt(ProjArgs a){
    __shared__ bhalf Tsh[64][72];
    const int r = blockIdx.x;
    if (r < 150){ const int bz = r / 30, rem = r % 30;
        if (bz == 4) gemm_vt_body<768>(rem % 6, rem / 6, a.ctx_all + (size_t)4 * 336 * 768, a.wv2T, a.vt_bg, 336, 384, 384, Tsh);
        else gemm_vt_body<768>(rem % 6, rem / 6, a.ctx_all + (size_t)bz * 336 * 768, a.wvobjT, a.vt_obj + (size_t)bz * 320 * 384, 336, 384, 384, Tsh);
    }
    else { const int s = r - 150; gemm_vt_body<320>(s % 64, s / 64, a.x_la, a.lawvT, a.vt_l, 4096, 4096, 4096, Tsh); }
}

// ================================================================ LayerNorm over f32 rows (Sbuf -> q2), wave-per-row
__global__ __launch_bounds__(256) void ln_rows_kernel(
    const float* __restrict__ in, const float* __restrict__ g, const float* __restrict__ b,
    bhalf* __restrict__ out)
{
    const int lane = threadIdx.x & 63;
    const int wgid = blockIdx.x * 4 + (threadIdx.x >> 6);   // 1024 blocks x 4 waves
    for (int row = wgid; row < 4096; row += 4096){
        float v[5];
        float s = 0.f, sq = 0.f;
#pragma unroll
        for (int j = 0; j < 5; ++j){
            v[j] = in[(long)row * 320 + lane + 64 * j];
            s += v[j]; sq += v[j] * v[j];
        }
#pragma unroll
        for (int o = 1; o < 64; o <<= 1){ s += __shfl_xor(s, o); sq += __shfl_xor(sq, o); }
        const float mean = s * (1.f / 320.f);
        const float var  = sq * (1.f / 320.f) - mean * mean;
        const float inv  = rsqrtf(var + 1e-5f);
#pragma unroll
        for (int j = 0; j < 5; ++j){
            const int c = lane + 64 * j;
            out[(long)row * 320 + c] = f2bf((v[j] - mean) * inv * g[c] + b[c]);
        }
    }
}

// ================================================================ standalone GEMM (modes 5 / 6 / 8), K=320 compile-time
template<int MODE>
__global__ __launch_bounds__(256) void gemm320(
    const bhalf* __restrict__ A, const bhalf* __restrict__ Wt,
    const float* __restrict__ bias, bhalf* __restrict__ Cbf,
    float* __restrict__ Cf, const float* __restrict__ add1, const float* __restrict__ add2,
    int M, int kdm, float ascale,
    const bhalf* __restrict__ A2, const bhalf* __restrict__ Wt2, const float* __restrict__ bias2)
{
    constexpr int K = 320;
    const int wave = threadIdx.x >> 6, lane = threadIdx.x & 63;
    const int m0 = blockIdx.x * 64 + wave * 16;
    const int n0 = blockIdx.y * 64;
    int mrow = m0 + (lane & 15); if (mrow > M - 1) mrow = M - 1;
    const int klo = (lane >> 4) * 8;
    const bhalf* ap = A + (long)mrow * K + klo;
    const bhalf* wp = Wt + (long)(n0 + (lane & 15)) * K + klo;
    const f32x4 fz = {0.f, 0.f, 0.f, 0.f};
    f32x4 acc[4]; acc[0] = fz; acc[1] = fz; acc[2] = fz; acc[3] = fz;
#pragma unroll
    for (int k0 = 0; k0 < K; k0 += 32){
        s16x8 a = *(const s16x8*)(ap + k0);
#pragma unroll
        for (int t = 0; t < 4; ++t){
            s16x8 b = *(const s16x8*)(wp + (long)t * 16 * K + k0);
            acc[t] = __builtin_amdgcn_mfma_f32_16x16x32_bf16(a, b, acc[t], 0, 0, 0);
        }
    }
    if (MODE == 6){
        const bhalf* ap2 = A2 + (long)mrow * K + klo;
        const bhalf* wp2 = Wt2 + (long)(n0 + (lane & 15)) * K + klo;
#pragma unroll
        for (int k0 = 0; k0 < K; k0 += 32){
            s16x8 a = *(const s16x8*)(ap2 + k0);
#pragma unroll
            for (int t = 0; t < 4; ++t){
                s16x8 b = *(const s16x8*)(wp2 + (long)t * 16 * K + k0);
                acc[t] = __builtin_amdgcn_mfma_f32_16x16x32_bf16(a, b, acc[t], 0, 0, 0);
            }
        }
    }
    if (MODE == 8){
#pragma unroll
        for (int i = 1; i < 4; ++i){
            const bhalf* api = A + (long)i * kdm + (long)mrow * K + klo;
#pragma unroll
            for (int k0 = 0; k0 < K; k0 += 32){
                s16x8 a = *(const s16x8*)(api + k0);
#pragma unroll
                for (int t = 0; t < 4; ++t){
                    s16x8 b = *(const s16x8*)(wp + (long)t * 16 * K + k0);
                    acc[t] = __builtin_amdgcn_mfma_f32_16x16x32_bf16(a, b, acc[t], 0, 0, 0);
                }
            }
        }
    }
    const int rb = m0 + (lane >> 4) * 4;
    int rin[4], rn[4];
    if (MODE == 5){
#pragma unroll
        for (int r = 0; r < 4; ++r){ const int row = rb + r; rin[r] = row / kdm; rn[r] = row % kdm; }
    }
#pragma unroll
    for (int t = 0; t < 4; ++t){
        const int col = n0 + t * 16 + (lane & 15);
        const int hh = col / 40, cc = col % 40;
#pragma unroll
        for (int r = 0; r < 4; ++r){
            const int row = rb + r;
            if (row >= M) continue;
            const float v = acc[t][r];
            if (MODE == 5)
                Cbf[(((long)rin[r] * 8 + hh) * kdm + rn[r]) * 40 + cc] = f2bf(v * ascale);
            else if (MODE == 6){
                const long o = (long)row * 320 + col;
                Cf[o] = v + bias[col] + bias2[col] + add1[o] + add2[o];
            }
            else if (MODE == 8){
                const long o = (long)row * 320 + col;
                float ssum = 0.f, cax = 0.f;
#pragma unroll
                for (int i = 0; i < 4; ++i){
                    const float sg = add2[i * 4096 + row];
                    ssum += sg;
                    cax += sg * add1[(long)i * 4096 * 320 + o];
                }
                Cf[o] = v + ssum * bias[col] + cax;
            }
        }
    }
}

// ================================================================ flash attention v4: fixed-max softmax (m == 0).
// Q pre-scaled by K2E at projection; p = exp2(score). Masked/tail lanes d=NEG_INF -> p = +0.
template<bool GMM, bool PARTIAL, bool SIG>
__global__ __launch_bounds__(256) void flash4(
    const bhalf* __restrict__ Qh, const bhalf* __restrict__ Kh, const bhalf* __restrict__ Vt,
    bhalf* __restrict__ O, const u64* __restrict__ maskb,
    int NKV, long qh_is, long qh_hs, long kh_is, long kh_hs, long vt_is, int vt_ns, long o_is,
    const float* __restrict__ sigp, bhalf* __restrict__ pacc, float* __restrict__ pl)
{
    const int lane = threadIdx.x & 63, wave = threadIdx.x >> 6;
    const int l15 = lane & 15, hi = lane >> 4, klo = hi * 8;
    const int h = blockIdx.y;
    const int inst = PARTIAL ? 0 : blockIdx.z;
    const int g = PARTIAL ? blockIdx.z : 0;
    const int qbase = blockIdx.x * 256 + wave * 64;
    const s16x8 z8 = {0, 0, 0, 0, 0, 0, 0, 0};
    const f32x4 fz = {0.f, 0.f, 0.f, 0.f};

    s16x8 qa0[4], qa1[4];
#pragma unroll
    for (int qg = 0; qg < 4; ++qg){
        const bhalf* qp = Qh + inst * qh_is + h * qh_hs + (long)(qbase + qg * 16 + l15) * 40;
        qa0[qg] = *(const s16x8*)(qp + klo);
        qa1[qg] = (hi == 0) ? *(const s16x8*)(qp + 32) : z8;
    }
    const int krbase = 8 * (l15 >> 2) + (l15 & 3);
    const bhalf* khead = Kh + inst * kh_is + h * kh_hs;
    const bhalf* kbase = khead + (long)krbase * 40;

    const bhalf* vbase[3];
#pragma unroll
    for (int ct = 0; ct < 3; ++ct){
        int dr = h * 40 + ct * 16 + l15; if (dr > 319) dr = 319;
        vbase[ct] = Vt + inst * vt_is + (long)dr * vt_ns + hi * 8;
    }

    f32x4 acc[4][3];
    float l_run[4];
#pragma unroll
    for (int qg = 0; qg < 4; ++qg){
        acc[qg][0] = fz; acc[qg][1] = fz; acc[qg][2] = fz;
        l_run[qg] = 0.f;
    }

    auto soft_pv = [&](f32x4 (&d)[4], s16x8 (&vb)[3][2], float& lr, f32x4 (&ac)[3]){
        float csum = 0.f;
#pragma unroll
        for (int t = 0; t < 4; ++t)
#pragma unroll
            for (int r = 0; r < 4; ++r){
                const float p = fexp2(d[t][r]);
                d[t][r] = p; csum += p;
            }
        csum += __shfl_xor(csum, 16);
        csum += __shfl_xor(csum, 32);
        lr += csum;
#pragma unroll
        for (int s = 0; s < 2; ++s){
            union { u32 w[4]; s16x8 v; } pb;
            pb.w[0] = cvtpk(d[2 * s][0], d[2 * s][1]);
            pb.w[1] = cvtpk(d[2 * s][2], d[2 * s][3]);
            pb.w[2] = cvtpk(d[2 * s + 1][0], d[2 * s + 1][1]);
            pb.w[3] = cvtpk(d[2 * s + 1][2], d[2 * s + 1][3]);
#pragma unroll
            for (int ct = 0; ct < 3; ++ct)
                ac[ct] = __builtin_amdgcn_mfma_f32_16x16x32_bf16(vb[ct][s], pb.v, ac[ct], 0, 0, 0);
        }
    };

    const int ch0 = PARTIAL ? g * 8 : 0;
    const int chN = PARTIAL ? ch0 + 8 : (NKV >> 6);
    for (int ch = ch0; ch < chN; ++ch){
        const int c0 = ch << 6;
        s16x8 k0[4], k1[4];
#pragma unroll
        for (int t = 0; t < 4; ++t){
            const int toff = ((t >> 1) << 5) + ((t & 1) << 2);
            const bhalf* kp = kbase + (long)(c0 + toff) * 40;
            k0[t] = *(const s16x8*)(kp + klo);
            k1[t] = (hi == 0) ? *(const s16x8*)(kp + 32) : z8;
        }
        s16x8 vb[3][2];
#pragma unroll
        for (int ct = 0; ct < 3; ++ct)
#pragma unroll
            for (int s = 0; s < 2; ++s)
                vb[ct][s] = *(const s16x8*)(vbase[ct] + c0 + 32 * s);
        u64 M[4];
        if (GMM){
#pragma unroll
            for (int qg = 0; qg < 4; ++qg)
                M[qg] = maskb[(long)ch * 4096 + qbase + qg * 16 + l15];
        }
#pragma unroll
        for (int qg = 0; qg < 4; ++qg){
            f32x4 d[4];
#pragma unroll
            for (int t = 0; t < 4; ++t){
                d[t] = __builtin_amdgcn_mfma_f32_16x16x32_bf16(k0[t], qa0[qg], fz, 0, 0, 0);
                d[t] = __builtin_amdgcn_mfma_f32_16x16x32_bf16(k1[t], qa1[qg], d[t], 0, 0, 0);
            }
            if (GMM && !__all(M[qg] == ~0ull)){
                const u64 Mh = M[qg] >> (hi * 8);
#pragma unroll
                for (int t = 0; t < 4; ++t){
                    const int tb = ((t >> 1) << 5) + ((t & 1) << 2);
#pragma unroll
                    for (int r = 0; r < 4; ++r)
                        if (!((Mh >> (tb + r)) & 1)) d[t][r] = NEG_INF;
                }
            }
            soft_pv(d, vb, l_run[qg], acc[qg]);
        }
    }
    if (!PARTIAL && (NKV & 63)){
        const int c0 = (NKV >> 6) << 6;
        s16x8 k0[4], k1[4];
#pragma unroll
        for (int t = 0; t < 4; ++t){
            const int toff = ((t >> 1) << 5) + ((t & 1) << 2);
            int kr = c0 + toff + krbase; if (kr > NKV - 1) kr = NKV - 1;
            const bhalf* kp = khead + (long)kr * 40;
            k0[t] = *(const s16x8*)(kp + klo);
            k1[t] = (hi == 0) ? *(const s16x8*)(kp + 32) : z8;
        }
        s16x8 vb[3][2];
#pragma unroll
        for (int ct = 0; ct < 3; ++ct)
#pragma unroll
            for (int s = 0; s < 2; ++s)
                vb[ct][s] = *(const s16x8*)(vbase[ct] + c0 + 32 * s);
#pragma unroll
        for (int qg = 0; qg < 4; ++qg){
            f32x4 d[4];
#pragma unroll
            for (int t = 0; t < 4; ++t){
                d[t] = __builtin_amdgcn_mfma_f32_16x16x32_bf16(k0[t], qa0[qg], fz, 0, 0, 0);
                d[t] = __builtin_amdgcn_mfma_f32_16x16x32_bf16(k1[t], qa1[qg], d[t], 0, 0, 0);
            }
#pragma unroll
            for (int t = 0; t < 4; ++t){
                const int tb = ((t >> 1) << 5) + ((t & 1) << 2);
#pragma unroll
                for (int r = 0; r < 4; ++r)
                    if (c0 + tb + hi * 8 + r >= NKV) d[t][r] = NEG_INF;
            }
            soft_pv(d, vb, l_run[qg], acc[qg]);
        }
    }

    if (PARTIAL){
#pragma unroll
        for (int qg = 0; qg < 4; ++qg){
            const int q = qbase + qg * 16 + l15;
#pragma unroll
            for (int ct = 0; ct < 3; ++ct){
                bhalf* pb = pacc + ((((size_t)(g * 8 + h) * 3 + ct) * 4 + hi) * 4096 + q) * 4;
                uint2 w;
                w.x = cvtpk(acc[qg][ct][0], acc[qg][ct][1]);
                w.y = cvtpk(acc[qg][ct][2], acc[qg][ct][3]);
                *(uint2*)pb = w;
            }
            if (hi == 0)
                pl[(size_t)(g * 8 + h) * 4096 + q] = l_run[qg];
        }
    } else {
#pragma unroll
        for (int qg = 0; qg < 4; ++qg){
            const int q = qbase + qg * 16 + l15;
            float sc = 1.f / l_run[qg];
            if (SIG) sc *= sigp[(long)inst * 4096 + q];
            bhalf* op = O + inst * o_is + (long)q * 320 + h * 40;
#pragma unroll
            for (int ct = 0; ct < 3; ++ct){
                const int d0 = ct * 16 + hi * 4;
                if (d0 < 40){
                    uint2 w;
                    w.x = cvtpk(acc[qg][ct][0] * sc, acc[qg][ct][1] * sc);
                    w.y = cvtpk(acc[qg][ct][2] * sc, acc[qg][ct][3] * sc);
                    *(uint2*)(op + d0) = w;
                }
            }
        }
    }
}

// ================================================================ combine kv-split partials (fixed-max: plain sums)
__global__ __launch_bounds__(256) void combine_kernel(
    const bhalf* __restrict__ pacc, const float* __restrict__ pl, bhalf* __restrict__ O)
{
    const int idx = blockIdx.x * 256 + threadIdx.x;
    const int h = idx / (3 * 4096);
    const int r2 = idx % (3 * 4096);
    const int ct = r2 >> 12, q = r2 & 4095;
    float ls = 0.f;
#pragma unroll
    for (int g = 0; g < 8; ++g) ls += pl[(size_t)(g * 8 + h) * 4096 + q];
    float acc[16];
#pragma unroll
    for (int d = 0; d < 16; ++d) acc[d] = 0.f;
#pragma unroll
    for (int g = 0; g < 8; ++g){
#pragma unroll
        for (int hi = 0; hi < 4; ++hi){
            const ushort4 v = *(const ushort4*)(pacc + ((((size_t)(g * 8 + h) * 3 + ct) * 4 + hi) * 4096 + q) * 4);
            acc[hi * 4 + 0] += bf2f(v.x);
            acc[hi * 4 + 1] += bf2f(v.y);
            acc[hi * 4 + 2] += bf2f(v.z);
            acc[hi * 4 + 3] += bf2f(v.w);
        }
    }
    const float inv = 1.f / ls;
    bhalf* op = O + (size_t)q * 320 + h * 40 + ct * 16;
    if (ct < 2){
        u32 wb[8];
#pragma unroll
        for (int d = 0; d < 8; ++d) wb[d] = cvtpk(acc[2 * d] * inv, acc[2 * d + 1] * inv);
        *(uint4*)op       = make_uint4(wb[0], wb[1], wb[2], wb[3]);
        *(uint4*)(op + 8) = make_uint4(wb[4], wb[5], wb[6], wb[7]);
    } else {
        u32 wb[4];
#pragma unroll
        for (int d = 0; d < 4; ++d) wb[d] = cvtpk(acc[2 * d] * inv, acc[2 * d + 1] * inv);
        *(uint4*)op = make_uint4(wb[0], wb[1], wb[2], wb[3]);
    }
}

// ================================================================ host
extern "C" void kernel_launch(void* const* d_in, const int* in_sizes, int n_in,
                              void* d_out, int out_size, void* d_ws, size_t ws_size,
                              hipStream_t stream)
{
    (void)in_sizes; (void)n_in; (void)out_size; (void)ws_size;
    const float* ca_x   = (const float*)d_in[0];
    const float* gmask  = (const float*)d_in[1];
    const float* smask  = (const float*)d_in[2];
    const float* itok   = (const float*)d_in[3];
    const float* ctx    = (const float*)d_in[4];
    const float* box    = (const float*)d_in[5];
    const float* imgf   = (const float*)d_in[6];
    const float* bgf    = (const float*)d_in[7];
    const float* sgv    = (const float*)d_in[8];
    const float* Wq_obj = (const float*)d_in[9];
    const float* Wk_obj = (const float*)d_in[10];
    const float* Wv_obj = (const float*)d_in[11];
    const float* Wo_obj = (const float*)d_in[12];
    const float* bo_obj = (const float*)d_in[13];
    const float* g_obj  = (const float*)d_in[14];
    const float* b_obj  = (const float*)d_in[15];
    const float* Wq2    = (const float*)d_in[16];
    const float* Wk2    = (const float*)d_in[17];
    const float* Wv2    = (const float*)d_in[18];
    const float* Wo2    = (const float*)d_in[19];
    const float* bo2    = (const float*)d_in[20];
    const float* g2     = (const float*)d_in[21];
    const float* b2     = (const float*)d_in[22];
    const float* pnW1   = (const float*)d_in[23];
    const float* pnb1   = (const float*)d_in[24];
    const float* pnW2   = (const float*)d_in[25];
    const float* pnb2   = (const float*)d_in[26];
    const float* pnW3   = (const float*)d_in[27];
    const float* pnb3   = (const float*)d_in[28];
    const float* laWq   = (const float*)d_in[29];
    const float* laWk   = (const float*)d_in[30];
    const float* laWv   = (const float*)d_in[31];
    const float* laWo   = (const float*)d_in[32];
    const float* labo   = (const float*)d_in[33];

    char* wsp = (char*)d_ws; size_t off = 0;
    auto alloc = [&](size_t bytes) -> void* {
        void* p = wsp + off; off += (bytes + 255) & ~(size_t)255; return p;
    };
    bhalf* wqobjT = (bhalf*)alloc(320 * 320 * 2);
    bhalf* woobjT = (bhalf*)alloc(320 * 320 * 2);
    bhalf* wq2T   = (bhalf*)alloc(320 * 320 * 2);
    bhalf* wo2T   = (bhalf*)alloc(320 * 320 * 2);
    bhalf* lawqT  = (bhalf*)alloc(320 * 320 * 2);   // lawqT..lawkT contiguous (204800 % 256 == 0)
    bhalf* lawkT  = (bhalf*)alloc(320 * 320 * 2);
    bhalf* lawvT  = (bhalf*)alloc(320 * 320 * 2);
    bhalf* lawoT  = (bhalf*)alloc(320 * 320 * 2);
    bhalf* wkobjT = (bhalf*)alloc(768 * 320 * 2);
    bhalf* wvobjT = (bhalf*)alloc(768 * 320 * 2);
    bhalf* wk2T   = (bhalf*)alloc(768 * 320 * 2);
    bhalf* wv2T   = (bhalf*)alloc(768 * 320 * 2);
    float* gm_all = (float*)alloc(5 * 4096 * 4);
    float* sig    = (float*)alloc(4 * 4096 * 4);
    float* boxtok = (float*)alloc(4 * 768 * 4);
    u64*   maskb  = (u64*)alloc((size_t)64 * 4096 * 8);
    bhalf* ctx_all= (bhalf*)alloc((size_t)5 * 336 * 768 * 2);   // fg[4] then bg
    bhalf* q_in   = (bhalf*)alloc((size_t)16384 * 320 * 2);
    bhalf* x_la   = (bhalf*)alloc((size_t)4096 * 320 * 2);
    bhalf* k_obj  = (bhalf*)alloc((size_t)4 * 336 * 320 * 2);   // packed [4][8][336][40]
    bhalf* vt_obj = (bhalf*)alloc((size_t)4 * 320 * 384 * 2);
    bhalf* k_bg   = (bhalf*)alloc((size_t)336 * 320 * 2);       // packed [8][336][40]
    bhalf* vt_bg  = (bhalf*)alloc((size_t)320 * 384 * 2);
    bhalf* q_obj  = (bhalf*)alloc((size_t)16384 * 320 * 2);     // packed [4][8][4096][40], pre-scaled by K2E
    bhalf* o_obj  = (bhalf*)alloc((size_t)16384 * 320 * 2);     // sig-prescaled attention out
    float* Sbuf   = (float*)alloc((size_t)4096 * 320 * 4);
    bhalf* q2v    = (bhalf*)alloc((size_t)4096 * 320 * 2);
    bhalf* q2p    = (bhalf*)alloc((size_t)4096 * 320 * 2);      // packed [8][4096][40], pre-scaled
    bhalf* o2     = (bhalf*)alloc((size_t)4096 * 320 * 2);
    bhalf* qkl    = (bhalf*)alloc((size_t)2 * 4096 * 320 * 2);  // packed [16][4096][40]: q(pre-scaled) 0-7, k 8-15
    bhalf* vt_l   = (bhalf*)alloc((size_t)320 * 4096 * 2);
    bhalf* ol     = (bhalf*)alloc((size_t)4096 * 320 * 2);

    // kv-split partials alias the dead q_in..o_obj region (36.4 MB; pacc bf16 25.2 + pl 1 = 26.2 MB).
    bhalf* pacc = (bhalf*)q_in;                                       // [8g][8h][3ct][4hi][4096q][4] bf16
    float* pl   = (float*)(pacc + (size_t)8 * 8 * 3 * 4 * 4096 * 4);  // [8g*8h][4096] f32

    // ---- launch 1: mega_prep (posnet x16 | weight transpose | resize | wave-per-row LN + x_la copy)
    PrepArgs pa{};
    pa.itok = itok; pa.g_obj = g_obj; pa.b_obj = b_obj; pa.q_in = q_in; pa.x_la = x_la;
    pa.wt.in[0] = Wq_obj; pa.wt.out[0] = wqobjT;
    pa.wt.in[1] = Wo_obj; pa.wt.out[1] = woobjT;
    pa.wt.in[2] = Wq2;    pa.wt.out[2] = wq2T;
    pa.wt.in[3] = Wo2;    pa.wt.out[3] = wo2T;
    pa.wt.in[4] = laWq;   pa.wt.out[4] = lawqT;
    pa.wt.in[5] = laWk;   pa.wt.out[5] = lawkT;
    pa.wt.in[6] = laWv;   pa.wt.out[6] = lawvT;
    pa.wt.in[7] = laWo;   pa.wt.out[7] = lawoT;
    pa.wt.in[8] = Wk_obj; pa.wt.out[8] = wkobjT;
    pa.wt.in[9] = Wv_obj; pa.wt.out[9] = wvobjT;
    pa.wt.in[10] = Wk2;   pa.wt.out[10] = wk2T;
    pa.wt.in[11] = Wv2;   pa.wt.out[11] = wv2T;
    pa.gmask = gmask; pa.smask = smask; pa.sgv = sgv; pa.gm_all = gm_all; pa.sig = sig;
    pa.box = box; pa.W1 = pnW1; pa.b1 = pnb1; pa.W2 = pnW2; pa.b2 = pnb2; pa.W3 = pnW3; pa.b3 = pnb3;
    pa.tok = boxtok;
    mega_prep<<<dim3(2648), 320, 0, stream>>>(pa);

    // ---- launch 2: mega_mask (maskbits | context assembly)
    mega_mask<<<dim3(5296), 256, 0, stream>>>(gm_all, maskb, ctx, imgf, bgf, boxtok, ctx_all);

    // ---- launch 3+4: projections (packed 64x64-per-wave GEMMs | V-transpose GEMMs)
    ProjArgs pj{};
    pj.q_in = q_in; pj.ctx_all = ctx_all; pj.x_la = x_la;
    pj.wqobjT = wqobjT; pj.wkobjT = wkobjT; pj.wk2T = wk2T; pj.lawqT = lawqT;
    pj.wvobjT = wvobjT; pj.wv2T = wv2T; pj.lawvT = lawvT;
    pj.q_obj = q_obj; pj.k_obj = k_obj; pj.k_bg = k_bg; pj.qkl = qkl;
    pj.vt_obj = vt_obj; pj.vt_bg = vt_bg; pj.vt_l = vt_l;
    proj_packed<<<dim3(520), 256, 0, stream>>>(pj);
    proj_vt<<<dim3(470), 256, 0, stream>>>(pj);

    // ---- launch 5: ea_obj attention (epilogue x sig)
    flash4<false, false, true><<<dim3(16, 8, 4), 256, 0, stream>>>(q_obj, k_obj, vt_obj, o_obj, nullptr,
        335, (long)8 * 4096 * 40, (long)4096 * 40, (long)8 * 336 * 40, (long)336 * 40,
        (long)320 * 384, 384, (long)4096 * 320, sig, nullptr, nullptr);

    // ---- launch 6: quad O-proj -> Sbuf (+sig*ca_x + sig_sum*bo)
    gemm320<8><<<dim3(64, 5), 256, 0, stream>>>(o_obj, woobjT, bo_obj, nullptr, Sbuf,
        ca_x + (size_t)4096 * 320, sig, 4096, 4096 * 320, 1.f, nullptr, nullptr, nullptr);

    // ---- launch 7: q2 = LN(Sbuf), wave-per-row
    ln_rows_kernel<<<dim3(1024), 256, 0, stream>>>(Sbuf, g2, b2, q2v);

    // ---- launch 8: q2 projection (pre-scaled by K2E)
    gemm320<5><<<dim3(64, 5), 256, 0, stream>>>(q2v, wq2T, nullptr, q2p, nullptr, nullptr, nullptr,
        4096, 4096, K2E, nullptr, nullptr, nullptr);

    // ---- launch 9: ea2 (background) attention
    flash4<false, false, false><<<dim3(16, 8, 1), 256, 0, stream>>>(q2p, k_bg, vt_bg, o2, nullptr,
        334, 0, (long)4096 * 40, 0, (long)336 * 40, 0, 384, 0, nullptr, nullptr, nullptr);

    // ---- launch 10: layout self-attention, kv-split G=8 (partials alias dead region)
    flash4<true, true, false><<<dim3(16, 8, 8), 256, 0, stream>>>(qkl, qkl + (size_t)8 * 4096 * 40, vt_l, nullptr, maskb,
        4096, 0, (long)4096 * 40, 0, (long)4096 * 40, 0, 4096, 0, nullptr, pacc, pl);

    // ---- launch 11: combine partials -> ol
    combine_kernel<<<dim3(384), 256, 0, stream>>>(pacc, pl, ol);

    // ---- launch 12: out = ca_x[0] + S + (o2@Wo2 + bo2) + (ol@laWo + labo)
    gemm320<6><<<dim3(64, 5), 256, 0, stream>>>(o2, wo2T, bo2, nullptr, (float*)d_out, ca_x, Sbuf,
        4096, 1, 1.f, ol, lawoT, labo);
}